// Round 17
// baseline (35.533 us; speedup 1.0000x reference)
//
#include <hip/hip_runtime.h>

#ifndef __has_builtin
#define __has_builtin(x) 0
#endif

#if __has_builtin(__builtin_amdgcn_sdot4)
#define DOT4(a, b, c) __builtin_amdgcn_sdot4((a), (b), (c), false)
#else
__device__ __forceinline__ int dot4_sw(int a, int b, int c) {
#pragma unroll
    for (int k = 0; k < 4; ++k)
        c += (int)(signed char)((a >> (8 * k)) & 0xff) *
             (int)(signed char)((b >> (8 * k)) & 0xff);
    return c;
}
#define DOT4(a, b, c) dot4_sw((a), (b), (c))
#endif

#if __has_builtin(__builtin_amdgcn_sched_barrier)
#define SCHED_FENCE() __builtin_amdgcn_sched_barrier(0)
#else
#define SCHED_FENCE() asm volatile("" ::: "memory")
#endif

typedef float vfloat4 __attribute__((ext_vector_type(4)));

constexpr int CH   = 256;
constexpr int NPIX = 1024;   // 32*32
constexpr float BN_EPS = 1e-5f;

// WAVE-GRANULAR blocks: 64 threads = 1 wave = one 8-row octet of one (n,g).
// 16384 blocks stream through the CUs at wave granularity -> no lockstep
// start, no ragged drain, waves naturally phase-staggered (loads of some
// overlap compute of others). Zero LDS, zero s_barrier. SALU weight pack.
__global__ __launch_bounds__(64)
void bconv(const float* __restrict__ x,
           const float* __restrict__ wgt,
           const float* __restrict__ gamma,
           const float* __restrict__ beta,
           const float* __restrict__ rmean,
           const float* __restrict__ rvar,
           float* __restrict__ out) {
    const int lane = threadIdx.x;
    // bijective XCD-chunked swizzle (nwg=16384, q=2048): XCD k gets
    // n in [8k, 8k+8) -> conv + shortcut reads of an image share one L2.
    const int bid = blockIdx.x;
    const int swz = (bid & 7) * 2048 + (bid >> 3);
    const int oct = swz & 3;          // 8-row octet within image
    const int g   = (swz >> 2) & 63;  // group
    const int n   = swz >> 8;         // image

    const int row  = oct * 8 + (lane >> 3);
    const int col0 = (lane & 7) * 4;
    const int pix0 = row * 32 + col0;
    const float* xn = x + n * CH * NPIX;
    float* on = out + n * CH * NPIX;

    // ---- issue ALL 16 loads upfront: 12 conv rows + 4 shortcut ----
    vfloat4 xv[3][4];
#pragma unroll
    for (int kh = 0; kh < 3; ++kh) {
        const int rsc = min(max(row + 2 * kh - 2, 0), 31);  // clamp; mask later
        const float* rp = xn + g * 4 * NPIX + rsc * 32 + col0;
#pragma unroll
        for (int ci = 0; ci < 4; ++ci)
            xv[kh][ci] = *(const vfloat4*)(rp + ci * NPIX);
    }
    vfloat4 sc[4];
#pragma unroll
    for (int c2 = 0; c2 < 4; ++c2)
        sc[c2] = *(const vfloat4*)(xn + (c2 * 64 + g) * NPIX + pix0);
    SCHED_FENCE();   // loads may not sink below this point

    // ---- weights: SALU sign-pack (uniform int loads -> SGPRs; exact) ----
    const int* wb = (const int*)(wgt + g * 144);  // [c2][ci][tap] as ints
    int wq[4][9];
#pragma unroll
    for (int c2 = 0; c2 < 4; ++c2)
#pragma unroll
        for (int t = 0; t < 9; ++t) {
            int pk = 0;
#pragma unroll
            for (int ci = 0; ci < 4; ++ci) {
                const int b = wb[c2 * 36 + ci * 9 + t];
                const int s = ((b & 0x7fffffff) == 0) ? 0 : ((b < 0) ? -1 : 1);
                pk |= (s & 0xff) << (8 * ci);
            }
            wq[c2][t] = pk;
        }

    // ---- BN consts (uniform; exact numpy op order, no FMA) ----
    float inv[4], bias[4];
#pragma unroll
    for (int ci = 0; ci < 4; ++ci) {
        const int c = g * 4 + ci;
        float r  = __fdiv_rn(1.0f, __fsqrt_rn(__fadd_rn(rvar[c], BN_EPS)));
        inv[ci]  = __fmul_rn(gamma[c], r);
        bias[ci] = __fsub_rn(beta[c], __fmul_rn(rmean[c], inv[ci]));
    }

    // ---- BN + sign + pack int8x4 over ci (waits xv; sc stays in flight) ----
    int pkc[3][4];
#pragma unroll
    for (int kh = 0; kh < 3; ++kh) {
        const bool ok = (unsigned)(row + 2 * kh - 2) < 32u;
#pragma unroll
        for (int p = 0; p < 4; ++p) {
            int v = 0;
#pragma unroll
            for (int ci = 0; ci < 4; ++ci) {
                float h = __fadd_rn(__fmul_rn(xv[kh][ci][p], inv[ci]), bias[ci]);
                int s = (h > 0.f) ? 1 : ((h < 0.f) ? -1 : 0);
                v |= (s & 0xff) << (8 * ci);
            }
            pkc[kh][p] = ok ? v : 0;
        }
    }

    // ---- lateral halo from lane+-1 (8 lanes per row; edges masked) ----
    const bool le = (col0 == 0), re = (col0 == 28);
    int a[3][8];
#pragma unroll
    for (int kh = 0; kh < 3; ++kh) {
        int l2 = __shfl_up(pkc[kh][2], 1);
        int l3 = __shfl_up(pkc[kh][3], 1);
        int r0 = __shfl_down(pkc[kh][0], 1);
        int r1 = __shfl_down(pkc[kh][1], 1);
        a[kh][0] = le ? 0 : l2;
        a[kh][1] = le ? 0 : l3;
        a[kh][2] = pkc[kh][0]; a[kh][3] = pkc[kh][1];
        a[kh][4] = pkc[kh][2]; a[kh][5] = pkc[kh][3];
        a[kh][6] = re ? 0 : r0;
        a[kh][7] = re ? 0 : r1;
    }

    // ---- conv + channel shuffle + shortcut + NT store ----
#pragma unroll
    for (int c2 = 0; c2 < 4; ++c2) {
        vfloat4 o;
#pragma unroll
        for (int p = 0; p < 4; ++p) {
            int acc = 0;
#pragma unroll
            for (int kh = 0; kh < 3; ++kh)
#pragma unroll
                for (int kw = 0; kw < 3; ++kw)
                    acc = DOT4(a[kh][p + 2 * kw], wq[c2][kh * 3 + kw], acc);
            o[p] = __fadd_rn((float)acc, sc[c2][p]);
        }
        __builtin_nontemporal_store(o, (vfloat4*)(on + (c2 * 64 + g) * NPIX + pix0));
    }
}

extern "C" void kernel_launch(void* const* d_in, const int* in_sizes, int n_in,
                              void* d_out, int out_size, void* d_ws, size_t ws_size,
                              hipStream_t stream) {
    const float* x     = (const float*)d_in[0];
    const float* wgt   = (const float*)d_in[1];
    const float* gamma = (const float*)d_in[2];
    const float* beta  = (const float*)d_in[3];
    const float* rmean = (const float*)d_in[4];
    const float* rvar  = (const float*)d_in[5];
    float* out = (float*)d_out;

    const int N = in_sizes[0] / (CH * NPIX);  // 64
    bconv<<<N * 64 * 4, 64, 0, stream>>>(x, wgt, gamma, beta, rmean, rvar, out);
}

// Round 18
// 32.176 us; speedup vs baseline: 1.1043x; 1.1043x over previous
//
#include <hip/hip_runtime.h>

#ifndef __has_builtin
#define __has_builtin(x) 0
#endif

#if __has_builtin(__builtin_amdgcn_sdot4)
#define DOT4(a, b, c) __builtin_amdgcn_sdot4((a), (b), (c), false)
#else
__device__ __forceinline__ int dot4_sw(int a, int b, int c) {
#pragma unroll
    for (int k = 0; k < 4; ++k)
        c += (int)(signed char)((a >> (8 * k)) & 0xff) *
             (int)(signed char)((b >> (8 * k)) & 0xff);
    return c;
}
#define DOT4(a, b, c) dot4_sw((a), (b), (c))
#endif

#if __has_builtin(__builtin_amdgcn_sched_barrier)
#define SCHED_FENCE() __builtin_amdgcn_sched_barrier(0)
#else
#define SCHED_FENCE() asm volatile("" ::: "memory")
#endif

typedef float vfloat4 __attribute__((ext_vector_type(4)));

constexpr int CH   = 256;
constexpr int NPIX = 1024;   // 32*32
constexpr float BN_EPS = 1e-5f;

// R15 structure (best: 30.6us), single change: PLAIN stores instead of
// nontemporal. out (64MB) + x (64MB) both fit in the 256MB L3 -> dirty
// writes can sit in cache and write back after kernel end, removing up to
// 64MB from the kernel's critical HBM window. A/B vs R15's NT stores.
__global__ __launch_bounds__(256, 4)
void bconv(const float* __restrict__ x,
           const float* __restrict__ wgt,
           const float* __restrict__ gamma,
           const float* __restrict__ beta,
           const float* __restrict__ rmean,
           const float* __restrict__ rvar,
           float* __restrict__ out) {
    const int tid = threadIdx.x;
    // bijective XCD-chunked swizzle (nwg=2048, q=256): co-locates each
    // n-pair's 64 group-blocks on one XCD -> shortcut re-reads hit L2.
    const int bid = blockIdx.x;
    const int swz = (bid & 7) * 256 + (bid >> 3);
    const int n0  = (swz >> 6) * 2;
    const int g   = swz & 63;

    const int pix0 = tid * 4;
    const int row  = pix0 >> 5;
    const int col0 = pix0 & 31;
    const float* xnA = x + n0 * CH * NPIX;
    const float* xnB = xnA + CH * NPIX;
    float* onA = out + n0 * CH * NPIX;
    float* onB = onA + CH * NPIX;

    // ---- phase 1: issue ALL image-A loads (12 row + 4 shortcut) ----
    vfloat4 xvA[3][4];
#pragma unroll
    for (int kh = 0; kh < 3; ++kh) {
        const int rsc = min(max(row + 2 * kh - 2, 0), 31);
        const float* rp = xnA + g * 4 * NPIX + rsc * 32 + col0;
#pragma unroll
        for (int ci = 0; ci < 4; ++ci)
            xvA[kh][ci] = *(const vfloat4*)(rp + ci * NPIX);
    }
    vfloat4 scA[4];
#pragma unroll
    for (int c2 = 0; c2 < 4; ++c2)
        scA[c2] = *(const vfloat4*)(xnA + (c2 * 64 + g) * NPIX + pix0);
    SCHED_FENCE();   // A loads may not sink below this point

    // ---- weights: SALU sign-pack (uniform int loads -> SGPRs; exact) ----
    const int* wb = (const int*)(wgt + g * 144);  // [c2][ci][tap] as ints
    int wq[4][9];
#pragma unroll
    for (int c2 = 0; c2 < 4; ++c2)
#pragma unroll
        for (int t = 0; t < 9; ++t) {
            int pk = 0;
#pragma unroll
            for (int ci = 0; ci < 4; ++ci) {
                const int b = wb[c2 * 36 + ci * 9 + t];
                const int s = ((b & 0x7fffffff) == 0) ? 0 : ((b < 0) ? -1 : 1);
                pk |= (s & 0xff) << (8 * ci);
            }
            wq[c2][t] = pk;
        }

    // ---- BN consts (uniform; exact numpy op order, no FMA) ----
    float inv[4], bias[4];
#pragma unroll
    for (int ci = 0; ci < 4; ++ci) {
        const int c = g * 4 + ci;
        float r  = __fdiv_rn(1.0f, __fsqrt_rn(__fadd_rn(rvar[c], BN_EPS)));
        inv[ci]  = __fmul_rn(gamma[c], r);
        bias[ci] = __fsub_rn(beta[c], __fmul_rn(rmean[c], inv[ci]));
    }

    auto pack = [&](const vfloat4 xv[3][4], int pkc[3][4]) {
#pragma unroll
        for (int kh = 0; kh < 3; ++kh) {
            const bool ok = (unsigned)(row + 2 * kh - 2) < 32u;
#pragma unroll
            for (int p = 0; p < 4; ++p) {
                int v = 0;
#pragma unroll
                for (int ci = 0; ci < 4; ++ci) {
                    float h = __fadd_rn(__fmul_rn(xv[kh][ci][p], inv[ci]), bias[ci]);
                    int s = (h > 0.f) ? 1 : ((h < 0.f) ? -1 : 0);
                    v |= (s & 0xff) << (8 * ci);
                }
                pkc[kh][p] = ok ? v : 0;
            }
        }
    };

    const bool le = (col0 == 0), re = (col0 == 28);
    auto compute_store = [&](const int pkc[3][4], const vfloat4 sc[4], float* on) {
        int a[3][8];
#pragma unroll
        for (int kh = 0; kh < 3; ++kh) {
            int l2 = __shfl_up(pkc[kh][2], 1);
            int l3 = __shfl_up(pkc[kh][3], 1);
            int r0 = __shfl_down(pkc[kh][0], 1);
            int r1 = __shfl_down(pkc[kh][1], 1);
            a[kh][0] = le ? 0 : l2;
            a[kh][1] = le ? 0 : l3;
            a[kh][2] = pkc[kh][0]; a[kh][3] = pkc[kh][1];
            a[kh][4] = pkc[kh][2]; a[kh][5] = pkc[kh][3];
            a[kh][6] = re ? 0 : r0;
            a[kh][7] = re ? 0 : r1;
        }
#pragma unroll
        for (int c2 = 0; c2 < 4; ++c2) {
            vfloat4 o;
#pragma unroll
            for (int p = 0; p < 4; ++p) {
                int acc = 0;
#pragma unroll
                for (int kh = 0; kh < 3; ++kh)
#pragma unroll
                    for (int kw = 0; kw < 3; ++kw)
                        acc = DOT4(a[kh][p + 2 * kw], wq[c2][kh * 3 + kw], acc);
                o[p] = __fadd_rn((float)acc, sc[c2][p]);
            }
            // PLAIN store (A/B vs R15's nontemporal): let L2/L3 absorb,
            // write back after kernel end.
            *(vfloat4*)(on + (c2 * 64 + g) * NPIX + pix0) = o;
        }
    };

    // ---- phase 2: pack A (fine-grained vmcnt waits on xvA only) ----
    int pkcA[3][4];
    pack(xvA, pkcA);

    // ---- phase 3: issue ALL image-B row loads, pinned above compute-A ----
    vfloat4 xvB[3][4];
#pragma unroll
    for (int kh = 0; kh < 3; ++kh) {
        const int rsc = min(max(row + 2 * kh - 2, 0), 31);
        const float* rp = xnB + g * 4 * NPIX + rsc * 32 + col0;
#pragma unroll
        for (int ci = 0; ci < 4; ++ci)
            xvB[kh][ci] = *(const vfloat4*)(rp + ci * NPIX);
    }
    SCHED_FENCE();   // B loads may not sink below; compute-A may not hoist above

    // ---- phase 4: compute + store A (B loads in flight underneath) ----
    compute_store(pkcA, scA, onA);

    // ---- phase 5: issue B shortcut loads (L2-resident), then pack B ----
    vfloat4 scB[4];
#pragma unroll
    for (int c2 = 0; c2 < 4; ++c2)
        scB[c2] = *(const vfloat4*)(xnB + (c2 * 64 + g) * NPIX + pix0);
    SCHED_FENCE();   // scB issues before the B dot4 chain

    int pkcB[3][4];
    pack(xvB, pkcB);
    compute_store(pkcB, scB, onB);
}

extern "C" void kernel_launch(void* const* d_in, const int* in_sizes, int n_in,
                              void* d_out, int out_size, void* d_ws, size_t ws_size,
                              hipStream_t stream) {
    const float* x     = (const float*)d_in[0];
    const float* wgt   = (const float*)d_in[1];
    const float* gamma = (const float*)d_in[2];
    const float* beta  = (const float*)d_in[3];
    const float* rmean = (const float*)d_in[4];
    const float* rvar  = (const float*)d_in[5];
    float* out = (float*)d_out;

    const int N = in_sizes[0] / (CH * NPIX);  // 64
    bconv<<<(N / 2) * 64, 256, 0, stream>>>(x, wgt, gamma, beta, rmean, rvar, out);
}

// Round 19
// 32.049 us; speedup vs baseline: 1.1087x; 1.0039x over previous
//
#include <hip/hip_runtime.h>

#ifndef __has_builtin
#define __has_builtin(x) 0
#endif

#if __has_builtin(__builtin_amdgcn_sdot4)
#define DOT4(a, b, c) __builtin_amdgcn_sdot4((a), (b), (c), false)
#else
__device__ __forceinline__ int dot4_sw(int a, int b, int c) {
#pragma unroll
    for (int k = 0; k < 4; ++k)
        c += (int)(signed char)((a >> (8 * k)) & 0xff) *
             (int)(signed char)((b >> (8 * k)) & 0xff);
    return c;
}
#define DOT4(a, b, c) dot4_sw((a), (b), (c))
#endif

#if __has_builtin(__builtin_amdgcn_sched_barrier)
#define SCHED_FENCE() __builtin_amdgcn_sched_barrier(0)
#else
#define SCHED_FENCE() asm volatile("" ::: "memory")
#endif

typedef float vfloat4 __attribute__((ext_vector_type(4)));

constexpr int CH   = 256;
constexpr int NPIX = 1024;   // 32*32
constexpr float BN_EPS = 1e-5f;

// R15 (best, 30.6us) + WAVE-PHASE STAGGER: waves with odd (waveid^blockid)
// process image B first. Images are independent -> identical results, but
// half the waves load while the other half compute, breaking the global
// phase lockstep that capped VALUBusy/HBM/Occupancy all at ~31%.
__global__ __launch_bounds__(256, 4)
void bconv(const float* __restrict__ x,
           const float* __restrict__ wgt,
           const float* __restrict__ gamma,
           const float* __restrict__ beta,
           const float* __restrict__ rmean,
           const float* __restrict__ rvar,
           float* __restrict__ out) {
    const int tid = threadIdx.x;
    // bijective XCD-chunked swizzle (nwg=2048, q=256): co-locates each
    // n-pair's 64 group-blocks on one XCD -> shortcut re-reads hit L2.
    const int bid = blockIdx.x;
    const int swz = (bid & 7) * 256 + (bid >> 3);
    const int n0  = (swz >> 6) * 2;
    const int g   = swz & 63;

    const int pix0 = tid * 4;
    const int row  = pix0 >> 5;
    const int col0 = pix0 & 31;

    // wave-phase stagger: swap which image is "first" per wave parity
    const bool odd = (((tid >> 6) ^ bid) & 1) != 0;
    const float* xnA = x + (n0 + (odd ? 1 : 0)) * CH * NPIX;
    const float* xnB = x + (n0 + (odd ? 0 : 1)) * CH * NPIX;
    float* onA = out + (n0 + (odd ? 1 : 0)) * CH * NPIX;
    float* onB = out + (n0 + (odd ? 0 : 1)) * CH * NPIX;

    // ---- phase 1: issue ALL first-image loads (12 row + 4 shortcut) ----
    vfloat4 xvA[3][4];
#pragma unroll
    for (int kh = 0; kh < 3; ++kh) {
        const int rsc = min(max(row + 2 * kh - 2, 0), 31);
        const float* rp = xnA + g * 4 * NPIX + rsc * 32 + col0;
#pragma unroll
        for (int ci = 0; ci < 4; ++ci)
            xvA[kh][ci] = *(const vfloat4*)(rp + ci * NPIX);
    }
    vfloat4 scA[4];
#pragma unroll
    for (int c2 = 0; c2 < 4; ++c2)
        scA[c2] = *(const vfloat4*)(xnA + (c2 * 64 + g) * NPIX + pix0);
    SCHED_FENCE();   // first-image loads may not sink below this point

    // ---- weights: SALU sign-pack (uniform int loads -> SGPRs; exact) ----
    const int* wb = (const int*)(wgt + g * 144);  // [c2][ci][tap] as ints
    int wq[4][9];
#pragma unroll
    for (int c2 = 0; c2 < 4; ++c2)
#pragma unroll
        for (int t = 0; t < 9; ++t) {
            int pk = 0;
#pragma unroll
            for (int ci = 0; ci < 4; ++ci) {
                const int b = wb[c2 * 36 + ci * 9 + t];
                const int s = ((b & 0x7fffffff) == 0) ? 0 : ((b < 0) ? -1 : 1);
                pk |= (s & 0xff) << (8 * ci);
            }
            wq[c2][t] = pk;
        }

    // ---- BN consts (uniform; exact numpy op order, no FMA) ----
    float inv[4], bias[4];
#pragma unroll
    for (int ci = 0; ci < 4; ++ci) {
        const int c = g * 4 + ci;
        float r  = __fdiv_rn(1.0f, __fsqrt_rn(__fadd_rn(rvar[c], BN_EPS)));
        inv[ci]  = __fmul_rn(gamma[c], r);
        bias[ci] = __fsub_rn(beta[c], __fmul_rn(rmean[c], inv[ci]));
    }

    auto pack = [&](const vfloat4 xv[3][4], int pkc[3][4]) {
#pragma unroll
        for (int kh = 0; kh < 3; ++kh) {
            const bool ok = (unsigned)(row + 2 * kh - 2) < 32u;
#pragma unroll
            for (int p = 0; p < 4; ++p) {
                int v = 0;
#pragma unroll
                for (int ci = 0; ci < 4; ++ci) {
                    float h = __fadd_rn(__fmul_rn(xv[kh][ci][p], inv[ci]), bias[ci]);
                    int s = (h > 0.f) ? 1 : ((h < 0.f) ? -1 : 0);
                    v |= (s & 0xff) << (8 * ci);
                }
                pkc[kh][p] = ok ? v : 0;
            }
        }
    };

    const bool le = (col0 == 0), re = (col0 == 28);
    auto compute_store = [&](const int pkc[3][4], const vfloat4 sc[4], float* on) {
        int a[3][8];
#pragma unroll
        for (int kh = 0; kh < 3; ++kh) {
            int l2 = __shfl_up(pkc[kh][2], 1);
            int l3 = __shfl_up(pkc[kh][3], 1);
            int r0 = __shfl_down(pkc[kh][0], 1);
            int r1 = __shfl_down(pkc[kh][1], 1);
            a[kh][0] = le ? 0 : l2;
            a[kh][1] = le ? 0 : l3;
            a[kh][2] = pkc[kh][0]; a[kh][3] = pkc[kh][1];
            a[kh][4] = pkc[kh][2]; a[kh][5] = pkc[kh][3];
            a[kh][6] = re ? 0 : r0;
            a[kh][7] = re ? 0 : r1;
        }
#pragma unroll
        for (int c2 = 0; c2 < 4; ++c2) {
            vfloat4 o;
#pragma unroll
            for (int p = 0; p < 4; ++p) {
                int acc = 0;
#pragma unroll
                for (int kh = 0; kh < 3; ++kh)
#pragma unroll
                    for (int kw = 0; kw < 3; ++kw)
                        acc = DOT4(a[kh][p + 2 * kw], wq[c2][kh * 3 + kw], acc);
                o[p] = __fadd_rn((float)acc, sc[c2][p]);
            }
            // out is never re-read: nontemporal keeps L2 for x
            __builtin_nontemporal_store(o, (vfloat4*)(on + (c2 * 64 + g) * NPIX + pix0));
        }
    };

    // ---- phase 2: pack first image (vmcnt waits on its rows only) ----
    int pkcA[3][4];
    pack(xvA, pkcA);

    // ---- phase 3: issue second-image row loads, pinned above compute ----
    vfloat4 xvB[3][4];
#pragma unroll
    for (int kh = 0; kh < 3; ++kh) {
        const int rsc = min(max(row + 2 * kh - 2, 0), 31);
        const float* rp = xnB + g * 4 * NPIX + rsc * 32 + col0;
#pragma unroll
        for (int ci = 0; ci < 4; ++ci)
            xvB[kh][ci] = *(const vfloat4*)(rp + ci * NPIX);
    }
    SCHED_FENCE();   // B loads may not sink below; compute-A may not hoist above

    // ---- phase 4: compute + store first image (B loads in flight) ----
    compute_store(pkcA, scA, onA);

    // ---- phase 5: issue B shortcut loads (L2-resident), then pack B ----
    vfloat4 scB[4];
#pragma unroll
    for (int c2 = 0; c2 < 4; ++c2)
        scB[c2] = *(const vfloat4*)(xnB + (c2 * 64 + g) * NPIX + pix0);
    SCHED_FENCE();   // scB issues before the B dot4 chain

    int pkcB[3][4];
    pack(xvB, pkcB);
    compute_store(pkcB, scB, onB);
}

extern "C" void kernel_launch(void* const* d_in, const int* in_sizes, int n_in,
                              void* d_out, int out_size, void* d_ws, size_t ws_size,
                              hipStream_t stream) {
    const float* x     = (const float*)d_in[0];
    const float* wgt   = (const float*)d_in[1];
    const float* gamma = (const float*)d_in[2];
    const float* beta  = (const float*)d_in[3];
    const float* rmean = (const float*)d_in[4];
    const float* rvar  = (const float*)d_in[5];
    float* out = (float*)d_out;

    const int N = in_sizes[0] / (CH * NPIX);  // 64
    bconv<<<(N / 2) * 64, 256, 0, stream>>>(x, wgt, gamma, beta, rmean, rvar, out);
}

// Round 20
// 31.817 us; speedup vs baseline: 1.1168x; 1.0073x over previous
//
#include <hip/hip_runtime.h>

#ifndef __has_builtin
#define __has_builtin(x) 0
#endif

#if __has_builtin(__builtin_amdgcn_sdot4)
#define DOT4(a, b, c) __builtin_amdgcn_sdot4((a), (b), (c), false)
#else
__device__ __forceinline__ int dot4_sw(int a, int b, int c) {
#pragma unroll
    for (int k = 0; k < 4; ++k)
        c += (int)(signed char)((a >> (8 * k)) & 0xff) *
             (int)(signed char)((b >> (8 * k)) & 0xff);
    return c;
}
#define DOT4(a, b, c) dot4_sw((a), (b), (c))
#endif

#if __has_builtin(__builtin_amdgcn_sched_barrier)
#define SCHED_FENCE() __builtin_amdgcn_sched_barrier(0)
#else
#define SCHED_FENCE() asm volatile("" ::: "memory")
#endif

typedef float vfloat4 __attribute__((ext_vector_type(4)));

constexpr int CH   = 256;
constexpr int NPIX = 1024;   // 32*32
constexpr float BN_EPS = 1e-5f;

// PERSISTENT ping-pong pipeline. Grid 512 = 2 blocks/CU (one resident round,
// no re-dispatch). Each block owns (group g, image-octet m) and streams 8
// images with explicit A/B register double-buffer: load(n+1) in flight while
// process(n) computes. launch_bounds(256,2) lifts the VGPR cap to ~256 so the
// compiler CAN keep both buffers live (every straight-line variant compacted
// to 64 VGPR and serialized). Weights/BN SALU-packed once per 8 images.
__global__ __launch_bounds__(256, 2)
void bconv(const float* __restrict__ x,
           const float* __restrict__ wgt,
           const float* __restrict__ gamma,
           const float* __restrict__ beta,
           const float* __restrict__ rmean,
           const float* __restrict__ rvar,
           float* __restrict__ out) {
    const int tid = threadIdx.x;
    // XCD-chunked bijective swizzle (nwg=512, q=64): XCD k gets all 64 groups
    // of image-octet m=k -> per-XCD live set ~2-3MB < 4MB L2.
    const int bid = blockIdx.x;
    const int swz = (bid & 7) * 64 + (bid >> 3);
    const int g   = swz & 63;
    const int n0  = (swz >> 6) * 8;   // image octet base

    const int pix0 = tid * 4;
    const int row  = pix0 >> 5;
    const int col0 = pix0 & 31;

    // ---- weights: SALU sign-pack once (uniform -> SGPRs; exact int ops) ----
    const int* wb = (const int*)(wgt + g * 144);  // [c2][ci][tap] as ints
    int wq[4][9];
#pragma unroll
    for (int c2 = 0; c2 < 4; ++c2)
#pragma unroll
        for (int t = 0; t < 9; ++t) {
            int pk = 0;
#pragma unroll
            for (int ci = 0; ci < 4; ++ci) {
                const int b = wb[c2 * 36 + ci * 9 + t];
                const int s = ((b & 0x7fffffff) == 0) ? 0 : ((b < 0) ? -1 : 1);
                pk |= (s & 0xff) << (8 * ci);
            }
            wq[c2][t] = pk;
        }

    // ---- BN consts once (uniform; exact numpy op order, no FMA) ----
    float inv[4], bias[4];
#pragma unroll
    for (int ci = 0; ci < 4; ++ci) {
        const int c = g * 4 + ci;
        float r  = __fdiv_rn(1.0f, __fsqrt_rn(__fadd_rn(rvar[c], BN_EPS)));
        inv[ci]  = __fmul_rn(gamma[c], r);
        bias[ci] = __fsub_rn(beta[c], __fmul_rn(rmean[c], inv[ci]));
    }

    auto load_img = [&](int n, vfloat4 xv[3][4], vfloat4 sc[4]) {
        const float* xn = x + n * CH * NPIX;
#pragma unroll
        for (int kh = 0; kh < 3; ++kh) {
            const int rsc = min(max(row + 2 * kh - 2, 0), 31);  // clamp; mask later
            const float* rp = xn + g * 4 * NPIX + rsc * 32 + col0;
#pragma unroll
            for (int ci = 0; ci < 4; ++ci)
                xv[kh][ci] = *(const vfloat4*)(rp + ci * NPIX);
        }
#pragma unroll
        for (int c2 = 0; c2 < 4; ++c2)
            sc[c2] = *(const vfloat4*)(xn + (c2 * 64 + g) * NPIX + pix0);
    };

    const bool le = (col0 == 0), re = (col0 == 28);
    auto process = [&](int n, const vfloat4 xv[3][4], const vfloat4 sc[4]) {
        // BN + sign + pack int8x4 over ci (zero out-of-range rows)
        int pkc[3][4];
#pragma unroll
        for (int kh = 0; kh < 3; ++kh) {
            const bool ok = (unsigned)(row + 2 * kh - 2) < 32u;
#pragma unroll
            for (int p = 0; p < 4; ++p) {
                int v = 0;
#pragma unroll
                for (int ci = 0; ci < 4; ++ci) {
                    float h = __fadd_rn(__fmul_rn(xv[kh][ci][p], inv[ci]), bias[ci]);
                    int s = (h > 0.f) ? 1 : ((h < 0.f) ? -1 : 0);
                    v |= (s & 0xff) << (8 * ci);
                }
                pkc[kh][p] = ok ? v : 0;
            }
        }
        // lateral halo from lane+-1 (8 lanes per row; edges masked)
        int a[3][8];
#pragma unroll
        for (int kh = 0; kh < 3; ++kh) {
            int l2 = __shfl_up(pkc[kh][2], 1);
            int l3 = __shfl_up(pkc[kh][3], 1);
            int r0 = __shfl_down(pkc[kh][0], 1);
            int r1 = __shfl_down(pkc[kh][1], 1);
            a[kh][0] = le ? 0 : l2;
            a[kh][1] = le ? 0 : l3;
            a[kh][2] = pkc[kh][0]; a[kh][3] = pkc[kh][1];
            a[kh][4] = pkc[kh][2]; a[kh][5] = pkc[kh][3];
            a[kh][6] = re ? 0 : r0;
            a[kh][7] = re ? 0 : r1;
        }
        // conv + channel shuffle + shortcut + NT store
        float* on = out + n * CH * NPIX;
#pragma unroll
        for (int c2 = 0; c2 < 4; ++c2) {
            vfloat4 o;
#pragma unroll
            for (int p = 0; p < 4; ++p) {
                int acc = 0;
#pragma unroll
                for (int kh = 0; kh < 3; ++kh)
#pragma unroll
                    for (int kw = 0; kw < 3; ++kw)
                        acc = DOT4(a[kh][p + 2 * kw], wq[c2][kh * 3 + kw], acc);
                o[p] = __fadd_rn((float)acc, sc[c2][p]);
            }
            __builtin_nontemporal_store(o, (vfloat4*)(on + (c2 * 64 + g) * NPIX + pix0));
        }
    };

    // ---- ping-pong pipeline over 8 images (fully unrolled, static bufs) ----
    vfloat4 xvA[3][4], scA[4], xvB[3][4], scB[4];
    load_img(n0, xvA, scA);
#pragma unroll
    for (int ii = 0; ii < 4; ++ii) {
        const int n = n0 + 2 * ii;
        load_img(n + 1, xvB, scB);   // B in flight under process(A)
        SCHED_FENCE();
        process(n, xvA, scA);
        if (ii < 3) {
            load_img(n + 2, xvA, scA);   // A(next) in flight under process(B)
            SCHED_FENCE();
        }
        process(n + 1, xvB, scB);
    }
}

extern "C" void kernel_launch(void* const* d_in, const int* in_sizes, int n_in,
                              void* d_out, int out_size, void* d_ws, size_t ws_size,
                              hipStream_t stream) {
    const float* x     = (const float*)d_in[0];
    const float* wgt   = (const float*)d_in[1];
    const float* gamma = (const float*)d_in[2];
    const float* beta  = (const float*)d_in[3];
    const float* rmean = (const float*)d_in[4];
    const float* rvar  = (const float*)d_in[5];
    float* out = (float*)d_out;

    const int N = in_sizes[0] / (CH * NPIX);  // 64
    bconv<<<(N / 8) * 64, 256, 0, stream>>>(x, wgt, gamma, beta, rmean, rvar, out);
}

// Round 21
// 30.443 us; speedup vs baseline: 1.1672x; 1.0451x over previous
//
#include <hip/hip_runtime.h>

#ifndef __has_builtin
#define __has_builtin(x) 0
#endif

#if __has_builtin(__builtin_amdgcn_sdot4)
#define DOT4(a, b, c) __builtin_amdgcn_sdot4((a), (b), (c), false)
#else
__device__ __forceinline__ int dot4_sw(int a, int b, int c) {
#pragma unroll
    for (int k = 0; k < 4; ++k)
        c += (int)(signed char)((a >> (8 * k)) & 0xff) *
             (int)(signed char)((b >> (8 * k)) & 0xff);
    return c;
}
#define DOT4(a, b, c) dot4_sw((a), (b), (c))
#endif

#if __has_builtin(__builtin_amdgcn_sched_barrier)
#define SCHED_FENCE() __builtin_amdgcn_sched_barrier(0)
#else
#define SCHED_FENCE() asm volatile("" ::: "memory")
#endif

typedef float vfloat4 __attribute__((ext_vector_type(4)));

constexpr int CH   = 256;
constexpr int NPIX = 1024;   // 32*32
constexpr float BN_EPS = 1e-5f;

// R15 structure (best 30.6us) + LDS BALLAST occupancy throttle: 80KB/block
// -> 2 blocks/CU -> grid 2048 executes in 4 waves of residency. Within each
// round, XCD k's 64 resident blocks all work ONE image-pair (dispatch is
// round-robin over XCDs; swz maps them so) -> 2MB live/XCD < 4MB L2 -> the
// shortcut re-read actually hits L2. Traffic model says time=traffic/3.2TB/s;
// this attacks the 33MB FETCH term. R20 proved 16 waves/CU loses nothing.
__global__ __launch_bounds__(256, 2)
void bconv(const float* __restrict__ x,
           const float* __restrict__ wgt,
           const float* __restrict__ gamma,
           const float* __restrict__ beta,
           const float* __restrict__ rmean,
           const float* __restrict__ rvar,
           float* __restrict__ out) {
    __shared__ char ballast[81920];   // occupancy throttle: 2 blocks/CU
    const int tid = threadIdx.x;
    if ((size_t)x == 1) ballast[tid] = 1;   // never true; keeps LDS allocated

    // bijective XCD-chunked swizzle (nwg=2048, q=256): co-locates each
    // n-pair's 64 group-blocks on one XCD -> shortcut re-reads hit L2.
    const int bid = blockIdx.x;
    const int swz = (bid & 7) * 256 + (bid >> 3);
    const int n0  = (swz >> 6) * 2;
    const int g   = swz & 63;

    const int pix0 = tid * 4;
    const int row  = pix0 >> 5;
    const int col0 = pix0 & 31;
    const float* xnA = x + n0 * CH * NPIX;
    const float* xnB = xnA + CH * NPIX;
    float* onA = out + n0 * CH * NPIX;
    float* onB = onA + CH * NPIX;

    // ---- phase 1: issue ALL image-A loads (12 row + 4 shortcut) ----
    vfloat4 xvA[3][4];
#pragma unroll
    for (int kh = 0; kh < 3; ++kh) {
        const int rsc = min(max(row + 2 * kh - 2, 0), 31);
        const float* rp = xnA + g * 4 * NPIX + rsc * 32 + col0;
#pragma unroll
        for (int ci = 0; ci < 4; ++ci)
            xvA[kh][ci] = *(const vfloat4*)(rp + ci * NPIX);
    }
    vfloat4 scA[4];
#pragma unroll
    for (int c2 = 0; c2 < 4; ++c2)
        scA[c2] = *(const vfloat4*)(xnA + (c2 * 64 + g) * NPIX + pix0);
    SCHED_FENCE();   // A loads may not sink below this point

    // ---- weights: SALU sign-pack (uniform int loads -> SGPRs; exact) ----
    const int* wb = (const int*)(wgt + g * 144);  // [c2][ci][tap] as ints
    int wq[4][9];
#pragma unroll
    for (int c2 = 0; c2 < 4; ++c2)
#pragma unroll
        for (int t = 0; t < 9; ++t) {
            int pk = 0;
#pragma unroll
            for (int ci = 0; ci < 4; ++ci) {
                const int b = wb[c2 * 36 + ci * 9 + t];
                const int s = ((b & 0x7fffffff) == 0) ? 0 : ((b < 0) ? -1 : 1);
                pk |= (s & 0xff) << (8 * ci);
            }
            wq[c2][t] = pk;
        }

    // ---- BN consts (uniform; exact numpy op order, no FMA) ----
    float inv[4], bias[4];
#pragma unroll
    for (int ci = 0; ci < 4; ++ci) {
        const int c = g * 4 + ci;
        float r  = __fdiv_rn(1.0f, __fsqrt_rn(__fadd_rn(rvar[c], BN_EPS)));
        inv[ci]  = __fmul_rn(gamma[c], r);
        bias[ci] = __fsub_rn(beta[c], __fmul_rn(rmean[c], inv[ci]));
    }

    auto pack = [&](const vfloat4 xv[3][4], int pkc[3][4]) {
#pragma unroll
        for (int kh = 0; kh < 3; ++kh) {
            const bool ok = (unsigned)(row + 2 * kh - 2) < 32u;
#pragma unroll
            for (int p = 0; p < 4; ++p) {
                int v = 0;
#pragma unroll
                for (int ci = 0; ci < 4; ++ci) {
                    float h = __fadd_rn(__fmul_rn(xv[kh][ci][p], inv[ci]), bias[ci]);
                    int s = (h > 0.f) ? 1 : ((h < 0.f) ? -1 : 0);
                    v |= (s & 0xff) << (8 * ci);
                }
                pkc[kh][p] = ok ? v : 0;
            }
        }
    };

    const bool le = (col0 == 0), re = (col0 == 28);
    auto compute_store = [&](const int pkc[3][4], const vfloat4 sc[4], float* on) {
        int a[3][8];
#pragma unroll
        for (int kh = 0; kh < 3; ++kh) {
            int l2 = __shfl_up(pkc[kh][2], 1);
            int l3 = __shfl_up(pkc[kh][3], 1);
            int r0 = __shfl_down(pkc[kh][0], 1);
            int r1 = __shfl_down(pkc[kh][1], 1);
            a[kh][0] = le ? 0 : l2;
            a[kh][1] = le ? 0 : l3;
            a[kh][2] = pkc[kh][0]; a[kh][3] = pkc[kh][1];
            a[kh][4] = pkc[kh][2]; a[kh][5] = pkc[kh][3];
            a[kh][6] = re ? 0 : r0;
            a[kh][7] = re ? 0 : r1;
        }
#pragma unroll
        for (int c2 = 0; c2 < 4; ++c2) {
            vfloat4 o;
#pragma unroll
            for (int p = 0; p < 4; ++p) {
                int acc = 0;
#pragma unroll
                for (int kh = 0; kh < 3; ++kh)
#pragma unroll
                    for (int kw = 0; kw < 3; ++kw)
                        acc = DOT4(a[kh][p + 2 * kw], wq[c2][kh * 3 + kw], acc);
                o[p] = __fadd_rn((float)acc, sc[c2][p]);
            }
            // out is never re-read: nontemporal keeps L2/L3 for x
            __builtin_nontemporal_store(o, (vfloat4*)(on + (c2 * 64 + g) * NPIX + pix0));
        }
    };

    // ---- phase 2: pack A (fine-grained vmcnt waits on xvA only) ----
    int pkcA[3][4];
    pack(xvA, pkcA);

    // ---- phase 3: issue ALL image-B row loads, pinned above compute-A ----
    vfloat4 xvB[3][4];
#pragma unroll
    for (int kh = 0; kh < 3; ++kh) {
        const int rsc = min(max(row + 2 * kh - 2, 0), 31);
        const float* rp = xnB + g * 4 * NPIX + rsc * 32 + col0;
#pragma unroll
        for (int ci = 0; ci < 4; ++ci)
            xvB[kh][ci] = *(const vfloat4*)(rp + ci * NPIX);
    }
    SCHED_FENCE();   // B loads may not sink below; compute-A may not hoist above

    // ---- phase 4: compute + store A (B loads in flight underneath) ----
    compute_store(pkcA, scA, onA);

    // ---- phase 5: issue B shortcut loads (L2-resident), then pack B ----
    vfloat4 scB[4];
#pragma unroll
    for (int c2 = 0; c2 < 4; ++c2)
        scB[c2] = *(const vfloat4*)(xnB + (c2 * 64 + g) * NPIX + pix0);
    SCHED_FENCE();   // scB issues before the B dot4 chain

    int pkcB[3][4];
    pack(xvB, pkcB);
    compute_store(pkcB, scB, onB);
}

extern "C" void kernel_launch(void* const* d_in, const int* in_sizes, int n_in,
                              void* d_out, int out_size, void* d_ws, size_t ws_size,
                              hipStream_t stream) {
    const float* x     = (const float*)d_in[0];
    const float* wgt   = (const float*)d_in[1];
    const float* gamma = (const float*)d_in[2];
    const float* beta  = (const float*)d_in[3];
    const float* rmean = (const float*)d_in[4];
    const float* rvar  = (const float*)d_in[5];
    float* out = (float*)d_out;

    const int N = in_sizes[0] / (CH * NPIX);  // 64
    bconv<<<(N / 2) * 64, 256, 0, stream>>>(x, wgt, gamma, beta, rmean, rvar, out);
}